// Round 1
// baseline (340.734 us; speedup 1.0000x reference)
//
#include <hip/hip_runtime.h>
#include <stdint.h>

#define NPTS 131072
#define CINC 128
#define COUTC 128
#define WDIM 512
#define K3 27

typedef float f32x4 __attribute__((ext_vector_type(4)));
typedef __bf16 bf16x8 __attribute__((ext_vector_type(8)));

__device__ __forceinline__ unsigned short f2bf(float x){
  union { float f; uint32_t u; } v; v.f = x;
  uint32_t u = v.u;
  uint32_t r = (u + 0x7fffu + ((u >> 16) & 1u)) >> 16;
  return (unsigned short)r;
}

// styles = w @ (aw/sqrt(512)).T + bias; sn = styles * rsqrt(mean(styles^2))
__global__ void k_styles(const float* __restrict__ w, const float* __restrict__ aw,
                         const float* __restrict__ ab, float* __restrict__ sn){
  __shared__ float red[512];
  int t = threadIdx.x;
  int b = t >> 7, c = t & 127;
  const float* wr = w + b * WDIM;
  const float* ar = aw + c * WDIM;
  float s = 0.f;
  for (int d = 0; d < WDIM; d++) s += wr[d] * ar[d];
  s = s * 0.04419417382415922f + ab[c];   // 1/sqrt(512)
  red[t] = s * s;
  __syncthreads();
  for (int off = 256; off > 0; off >>= 1){
    if (t < off) red[t] += red[t + off];
    __syncthreads();
  }
  float ms = red[0] * (1.0f / 512.0f);
  sn[t] = s * rsqrtf(ms);
}

// wnorm[cout] = rsqrt(mean(cw[cout]^2))  over cin*27 = 3456
__global__ void k_wnorm(const float* __restrict__ cw, float* __restrict__ wnorm){
  __shared__ float red[256];
  int co = blockIdx.x, t = threadIdx.x;
  const float* p = cw + co * 3456;
  float s = 0.f;
  for (int i = t; i < 3456; i += 256){ float v = p[i]; s += v * v; }
  red[t] = s; __syncthreads();
  for (int off = 128; off > 0; off >>= 1){
    if (t < off) red[t] += red[t + off];
    __syncthreads();
  }
  if (t == 0) wnorm[co] = rsqrtf(red[0] * (1.0f / 3456.0f));
}

// dco2[b][cout] = rsqrt(sum_{cin,k}(wn*sn)^2 + 1e-8) * rsqrt(mag)
__global__ void k_dcoefs(const float* __restrict__ cw, const float* __restrict__ sn,
                         const float* __restrict__ wnorm, const float* __restrict__ mag,
                         float* __restrict__ dco2){
  int blk = blockIdx.x;            // b*128 + cout
  int b = blk >> 7, co = blk & 127;
  int lane = threadIdx.x;
  float sum = 0.f;
  for (int cin = lane; cin < CINC; cin += 64){
    float s = sn[b * CINC + cin]; float s2 = s * s;
    const float* p = cw + co * 3456 + cin * 27;
    float c2 = 0.f;
    for (int k = 0; k < 27; k++){ float v = p[k]; c2 += v * v; }
    sum += c2 * s2;
  }
  for (int off = 32; off > 0; off >>= 1) sum += __shfl_down(sum, off, 64);
  if (lane == 0){
    float wn2 = wnorm[co]; wn2 *= wn2;
    dco2[blk] = rsqrtf(sum * wn2 + 1e-8f) * rsqrtf(mag[0]);
  }
}

// bpack[k][kk][grp][lane][j] = bf16(wn[cout][cin][k]),
// cin = kk*32 + (lane>>4)*8 + j, cout = grp*16 + (lane&15)  (MFMA B-frag layout)
__global__ void k_bpack(const float* __restrict__ cw, const float* __restrict__ wnorm,
                        unsigned short* __restrict__ bpack){
  int blk = blockIdx.x;            // 27*32
  int k = blk >> 5; int rem = blk & 31; int kk = rem >> 3;
  int lane = threadIdx.x; int q = lane >> 4, m = lane & 15;
  int grp = rem & 7;
  int cout = grp * 16 + m;
  float ws = wnorm[cout];
  unsigned short* dst = bpack + (blk * 64 + lane) * 8;
  for (int j = 0; j < 8; j++){
    int cin = kk * 32 + q * 8 + j;
    dst[j] = f2bf(cw[cout * 3456 + cin * 27 + k] * ws);
  }
}

// xpad[n][c] = bf16(x[n][c] * sn[b][c]); row NPTS = zeros
__global__ void k_xmod(const float* __restrict__ x, const float* __restrict__ sn,
                       const int* __restrict__ bidx, unsigned short* __restrict__ xpad){
  int gid = blockIdx.x * 256 + threadIdx.x;          // one 4-elem group
  const int total = (NPTS + 1) * 32;
  if (gid >= total) return;
  int n = gid >> 5;
  int c4 = (gid & 31) * 4;
  unsigned short o0, o1, o2, o3;
  if (n < NPTS){
    int b = bidx[n];
    const float* xr = x + (size_t)n * CINC + c4;
    const float* sr = sn + b * CINC + c4;
    o0 = f2bf(xr[0] * sr[0]); o1 = f2bf(xr[1] * sr[1]);
    o2 = f2bf(xr[2] * sr[2]); o3 = f2bf(xr[3] * sr[3]);
  } else { o0 = o1 = o2 = o3 = 0; }
  *(ushort4*)(xpad + (size_t)n * CINC + c4) = make_ushort4(o0, o1, o2, o3);
}

__global__ void k_invinit(int* __restrict__ invT){
  int j = blockIdx.x * 256 + threadIdx.x;
  int k = blockIdx.y;
  invT[k * NPTS + j] = NPTS;
}

__global__ void k_invscat(const int* __restrict__ out_idx, const int* __restrict__ in_idx,
                          int* __restrict__ invT){
  int j = blockIdx.x * 256 + threadIdx.x;
  int k = blockIdx.y;
  int o = out_idx[k * NPTS + j];
  if (o < NPTS) invT[k * NPTS + o] = in_idx[k * NPTS + j];
}

// Main conv: block = 128 output points x 128 couts, 8 waves (4M x 2N),
// 27 taps x 4 K-chunks of 16x16x32 bf16 MFMA.
__global__ __launch_bounds__(512, 4) void k_conv(
    const unsigned short* __restrict__ xpad,
    const unsigned short* __restrict__ bpack,
    const int* __restrict__ invT,
    const float* __restrict__ dco2,
    const float* __restrict__ cbias,
    const int* __restrict__ bidx,
    float* __restrict__ out){
  __shared__ __align__(16) unsigned short Ash[128 * 128];  // 32KB, XOR-swizzled rows
  __shared__ __align__(16) unsigned short Bsh[16384];      // 32KB, frag-layout blob
  int t = threadIdx.x;
  int wave = t >> 6, lane = t & 63;
  int wm = wave >> 1, wn = wave & 1;
  int q = lane >> 4, m16 = lane & 15;
  int base_pt = blockIdx.x * 128;

  f32x4 acc[2][4];
  #pragma unroll
  for (int i = 0; i < 2; i++)
    #pragma unroll
    for (int j = 0; j < 4; j++) acc[i][j] = (f32x4){0.f, 0.f, 0.f, 0.f};

  for (int k = 0; k < K3; k++){
    __syncthreads();
    // stage B: contiguous 32KB copy
    {
      const int4* src = (const int4*)(bpack + k * 16384);
      int4* dstB = (int4*)Bsh;
      #pragma unroll
      for (int i = 0; i < 4; i++){
        int c = i * 512 + t;
        dstB[c] = src[c];
      }
    }
    // stage A: gather 128 rows of 256B via invT, XOR-swizzle 16B chunks
    {
      const int* invk = invT + k * NPTS + base_pt;
      #pragma unroll
      for (int i = 0; i < 4; i++){
        int chunk = i * 512 + t;
        int row = chunk >> 4, c = chunk & 15;
        int inv = invk[row];
        int4 v = *(const int4*)(xpad + (size_t)inv * CINC + c * 8);
        *(int4*)(Ash + row * 128 + ((c ^ row) & 15) * 8) = v;
      }
    }
    __syncthreads();
    #pragma unroll
    for (int kk = 0; kk < 4; kk++){
      int cA = (kk * 4 + q) ^ m16;            // swizzled chunk
      bf16x8 a0 = *(const bf16x8*)(Ash + (wm * 32 + m16) * 128 + (cA & 15) * 8);
      bf16x8 a1 = *(const bf16x8*)(Ash + (wm * 32 + 16 + m16) * 128 + (cA & 15) * 8);
      #pragma unroll
      for (int jn = 0; jn < 4; jn++){
        bf16x8 b = *(const bf16x8*)(Bsh + ((kk * 8 + wn * 4 + jn) * 64 + lane) * 8);
        acc[0][jn] = __builtin_amdgcn_mfma_f32_16x16x32_bf16(a0, b, acc[0][jn], 0, 0, 0);
        acc[1][jn] = __builtin_amdgcn_mfma_f32_16x16x32_bf16(a1, b, acc[1][jn], 0, 0, 0);
      }
    }
  }

  // epilogue: demod + bias + leaky*sqrt2 + clip
  const float S2 = 1.41421356237309515f;
  #pragma unroll
  for (int i = 0; i < 2; i++){
    #pragma unroll
    for (int r = 0; r < 4; r++){
      int row = wm * 32 + i * 16 + q * 4 + r;   // D: row=(lane>>4)*4+reg
      int n = base_pt + row;
      int b = bidx[n];
      const float* dc = dco2 + b * COUTC;
      float* orow = out + (size_t)n * COUTC;
      #pragma unroll
      for (int jn = 0; jn < 4; jn++){
        int col = wn * 64 + jn * 16 + m16;      // D: col=lane&15
        float v = acc[i][jn][r] * dc[col] + cbias[col];
        v = (v < 0.f ? 0.2f * v : v) * S2;
        v = fminf(fmaxf(v, -256.f), 256.f);
        orow[col] = v;
      }
    }
  }
}

extern "C" void kernel_launch(void* const* d_in, const int* in_sizes, int n_in,
                              void* d_out, int out_size, void* d_ws, size_t ws_size,
                              hipStream_t stream){
  const float* x   = (const float*)d_in[0];
  const float* w   = (const float*)d_in[1];
  const float* aw  = (const float*)d_in[2];
  const float* ab  = (const float*)d_in[3];
  const float* cw  = (const float*)d_in[4];
  const float* cb  = (const float*)d_in[5];
  const float* mag = (const float*)d_in[6];
  const int* bidx    = (const int*)d_in[7];
  const int* in_idx  = (const int*)d_in[8];
  const int* out_idx = (const int*)d_in[9];
  float* out = (float*)d_out;
  char* ws = (char*)d_ws;

  float* sn    = (float*)(ws + 0);          // 2048 B
  float* dco2  = (float*)(ws + 2048);       // 2048 B
  float* wnorm = (float*)(ws + 4096);       // 512 B
  unsigned short* bpack = (unsigned short*)(ws + 8192);     // 884736 B
  unsigned short* xpad  = (unsigned short*)(ws + 892928);   // 33554688 B
  int* invT    = (int*)(ws + 34447616);                     // 14155776 B -> end 48603392

  k_styles<<<1, 512, 0, stream>>>(w, aw, ab, sn);
  k_wnorm<<<128, 256, 0, stream>>>(cw, wnorm);
  k_dcoefs<<<512, 64, 0, stream>>>(cw, sn, wnorm, mag, dco2);
  k_bpack<<<864, 64, 0, stream>>>(cw, wnorm, bpack);
  k_xmod<<<16385, 256, 0, stream>>>(x, sn, bidx, xpad);
  dim3 gi(512, 27);
  k_invinit<<<gi, 256, 0, stream>>>(invT);
  k_invscat<<<gi, 256, 0, stream>>>(out_idx, in_idx, invT);
  k_conv<<<1024, 512, 0, stream>>>(xpad, bpack, invT, dco2, cb, bidx, out);
}

// Round 2
// 325.797 us; speedup vs baseline: 1.0458x; 1.0458x over previous
//
#include <hip/hip_runtime.h>
#include <stdint.h>

#define NPTS 131072
#define CINC 128
#define COUTC 128
#define WDIM 512
#define K3 27

typedef float f32x4 __attribute__((ext_vector_type(4)));
typedef __bf16 bf16x8 __attribute__((ext_vector_type(8)));

#define GLOAD_LDS16(g, l) \
  __builtin_amdgcn_global_load_lds((const __attribute__((address_space(1))) void*)(g), \
                                   (__attribute__((address_space(3))) void*)(l), 16, 0, 0)

__device__ __forceinline__ unsigned short f2bf(float x){
  union { float f; uint32_t u; } v; v.f = x;
  uint32_t u = v.u;
  uint32_t r = (u + 0x7fffu + ((u >> 16) & 1u)) >> 16;
  return (unsigned short)r;
}

// styles[b*128+c] = dot(w[b], aw[c])/sqrt(512) + ab[c]; 4 dots/block, 1/wave
__global__ void k_styles_dot(const float* __restrict__ w, const float* __restrict__ aw,
                             const float* __restrict__ ab, float* __restrict__ styles){
  int wave = threadIdx.x >> 6, lane = threadIdx.x & 63;
  int blk = blockIdx.x * 4 + wave;            // 512 dots
  int b = blk >> 7, c = blk & 127;
  const float4* wr = (const float4*)(w + b * WDIM);
  const float4* ar = (const float4*)(aw + c * WDIM);
  float4 w0 = wr[lane * 2], w1 = wr[lane * 2 + 1];
  float4 a0 = ar[lane * 2], a1 = ar[lane * 2 + 1];
  float s = w0.x * a0.x + w0.y * a0.y + w0.z * a0.z + w0.w * a0.w
          + w1.x * a1.x + w1.y * a1.y + w1.z * a1.z + w1.w * a1.w;
  for (int off = 32; off > 0; off >>= 1) s += __shfl_down(s, off, 64);
  if (lane == 0) styles[blk] = s * 0.04419417382415922f + ab[c];
}

// sn = styles * rsqrt(mean(styles^2))
__global__ void k_snorm(const float* __restrict__ styles, float* __restrict__ sn){
  __shared__ float red[512];
  int t = threadIdx.x;
  float s = styles[t];
  red[t] = s * s;
  __syncthreads();
  for (int off = 256; off > 0; off >>= 1){
    if (t < off) red[t] += red[t + off];
    __syncthreads();
  }
  sn[t] = s * rsqrtf(red[0] * (1.0f / 512.0f));
}

// per cout: wnorm + vmat[cout][cin]=sum_k cw^2 + bpack (B-frag layout, wn-scaled)
__global__ void k_prep_w(const float* __restrict__ cw, float* __restrict__ wnorm,
                         float* __restrict__ vmat, unsigned short* __restrict__ bpack){
  __shared__ float red[128];
  int co = blockIdx.x, cin = threadIdx.x;
  const float* p = cw + co * 3456 + cin * 27;
  float r[27];
  float v = 0.f;
  #pragma unroll
  for (int k = 0; k < 27; k++){ r[k] = p[k]; v += r[k] * r[k]; }
  vmat[co * 128 + cin] = v;
  red[cin] = v;
  __syncthreads();
  for (int off = 64; off > 0; off >>= 1){
    if (cin < off) red[cin] += red[cin + off];
    __syncthreads();
  }
  float wn_s = rsqrtf(red[0] * (1.0f / 3456.0f));
  if (cin == 0) wnorm[co] = wn_s;
  int grp = co >> 4, m = co & 15;
  int kk = cin >> 5, q = (cin >> 3) & 3, j = cin & 7;
  #pragma unroll
  for (int k = 0; k < 27; k++){
    int idx = ((k * 32 + kk * 8 + grp) * 64 + q * 16 + m) * 8 + j;
    bpack[idx] = f2bf(r[k] * wn_s);
  }
}

// dco2[b*128+co] = rsqrt(wn^2 * sum_cin(vmat*sn^2) + 1e-8) * rsqrt(mag)
__global__ void k_dcoefs2(const float* __restrict__ vmat, const float* __restrict__ sn,
                          const float* __restrict__ wnorm, const float* __restrict__ mag,
                          float* __restrict__ dco2){
  int wave = threadIdx.x >> 6, lane = threadIdx.x & 63;
  int pair = blockIdx.x * 8 + wave;          // b*128+co
  int b = pair >> 7, co = pair & 127;
  float s0 = sn[b * 128 + lane], s1 = sn[b * 128 + 64 + lane];
  float sum = vmat[co * 128 + lane] * s0 * s0 + vmat[co * 128 + 64 + lane] * s1 * s1;
  for (int off = 32; off > 0; off >>= 1) sum += __shfl_down(sum, off, 64);
  if (lane == 0){
    float wn = wnorm[co];
    dco2[pair] = rsqrtf(sum * wn * wn + 1e-8f) * rsqrtf(mag[0]);
  }
}

// xpad[n][c] = bf16(x[n][c] * sn[b][c]); row NPTS = zeros
__global__ void k_xmod(const float* __restrict__ x, const float* __restrict__ sn,
                       const int* __restrict__ bidx, unsigned short* __restrict__ xpad){
  int gid = blockIdx.x * 256 + threadIdx.x;
  const int total = (NPTS + 1) * 32;
  if (gid >= total) return;
  int n = gid >> 5;
  int c4 = (gid & 31) * 4;
  unsigned short o0, o1, o2, o3;
  if (n < NPTS){
    int b = bidx[n];
    float4 xv = *(const float4*)(x + (size_t)n * CINC + c4);
    float4 sv = *(const float4*)(sn + b * CINC + c4);
    o0 = f2bf(xv.x * sv.x); o1 = f2bf(xv.y * sv.y);
    o2 = f2bf(xv.z * sv.z); o3 = f2bf(xv.w * sv.w);
  } else { o0 = o1 = o2 = o3 = 0; }
  *(ushort4*)(xpad + (size_t)n * CINC + c4) = make_ushort4(o0, o1, o2, o3);
}

__global__ void k_invinit(int* __restrict__ invT){
  int j = blockIdx.x * 256 + threadIdx.x;
  int k = blockIdx.y;
  invT[k * NPTS + j] = NPTS;
}

__global__ void k_invscat(const int* __restrict__ out_idx, const int* __restrict__ in_idx,
                          int* __restrict__ invT){
  int j = blockIdx.x * 256 + threadIdx.x;
  int k = blockIdx.y;
  int o = out_idx[k * NPTS + j];
  if (o < NPTS) invT[k * NPTS + o] = in_idx[k * NPTS + j];
}

// Main conv: block = 128 output points x 128 couts, 8 waves (4M x 2N).
// A double-buffered via async global_load_lds (prefetch tap k+1 overlaps tap-k MFMA);
// B fragments loaded directly from global (L2-resident broadcast).
__global__ __launch_bounds__(512, 4) void k_conv(
    const unsigned short* __restrict__ xpad,
    const unsigned short* __restrict__ bpack,
    const int* __restrict__ invT,
    const float* __restrict__ dco2,
    const float* __restrict__ cbias,
    const int* __restrict__ bidx,
    float* __restrict__ out){
  __shared__ __align__(16) unsigned short Ash[2 * 128 * 128];  // 64KB double buffer
  int t = threadIdx.x;
  int wave = t >> 6, lane = t & 63;
  int wm = wave >> 1, wn = wave & 1;
  int q = lane >> 4, m16 = lane & 15;
  int base_pt = blockIdx.x * 128;

  f32x4 acc[2][4];
  #pragma unroll
  for (int i = 0; i < 2; i++)
    #pragma unroll
    for (int j = 0; j < 4; j++) acc[i][j] = (f32x4){0.f, 0.f, 0.f, 0.f};

  // prefetch tap k into buffer bufsel: source-lane XOR swizzle keeps LDS dest lane-linear
  auto prefetch = [&](int k, int bufsel){
    const int* invk = invT + k * NPTS + base_pt;
    unsigned short* Ab = Ash + bufsel * (128 * 128);
    #pragma unroll
    for (int i = 0; i < 4; i++){
      int chunk = i * 512 + t;
      int row = chunk >> 4, c = chunk & 15;
      int inv = invk[row];
      const unsigned short* src = xpad + (size_t)inv * CINC + ((c ^ row) & 15) * 8;
      GLOAD_LDS16(src, Ab + chunk * 8);
    }
  };

  prefetch(0, 0);
  for (int k = 0; k < K3; k++){
    __syncthreads();                      // drains prefetch(k); releases buf[(k+1)&1]
    if (k + 1 < K3) prefetch(k + 1, (k + 1) & 1);
    const unsigned short* Ab = Ash + (k & 1) * (128 * 128);
    const unsigned short* Bg = bpack + k * 16384;
    #pragma unroll
    for (int kk = 0; kk < 4; kk++){
      int cA = ((kk * 4 + q) ^ m16) & 15;
      bf16x8 a0 = *(const bf16x8*)(Ab + (wm * 32 + m16) * 128 + cA * 8);
      bf16x8 a1 = *(const bf16x8*)(Ab + (wm * 32 + 16 + m16) * 128 + cA * 8);
      #pragma unroll
      for (int jn = 0; jn < 4; jn++){
        bf16x8 b = *(const bf16x8*)(Bg + ((kk * 8 + wn * 4 + jn) * 64 + lane) * 8);
        acc[0][jn] = __builtin_amdgcn_mfma_f32_16x16x32_bf16(a0, b, acc[0][jn], 0, 0, 0);
        acc[1][jn] = __builtin_amdgcn_mfma_f32_16x16x32_bf16(a1, b, acc[1][jn], 0, 0, 0);
      }
    }
  }

  // epilogue: demod + bias + leaky*sqrt2 + clip
  const float S2 = 1.41421356237309515f;
  #pragma unroll
  for (int i = 0; i < 2; i++){
    #pragma unroll
    for (int r = 0; r < 4; r++){
      int row = wm * 32 + i * 16 + q * 4 + r;   // D: row=(lane>>4)*4+reg
      int n = base_pt + row;
      int b = bidx[n];
      const float* dc = dco2 + b * COUTC;
      float* orow = out + (size_t)n * COUTC;
      #pragma unroll
      for (int jn = 0; jn < 4; jn++){
        int col = wn * 64 + jn * 16 + m16;      // D: col=lane&15
        float v = acc[i][jn][r] * dc[col] + cbias[col];
        v = (v < 0.f ? 0.2f * v : v) * S2;
        v = fminf(fmaxf(v, -256.f), 256.f);
        orow[col] = v;
      }
    }
  }
}

extern "C" void kernel_launch(void* const* d_in, const int* in_sizes, int n_in,
                              void* d_out, int out_size, void* d_ws, size_t ws_size,
                              hipStream_t stream){
  const float* x   = (const float*)d_in[0];
  const float* w   = (const float*)d_in[1];
  const float* aw  = (const float*)d_in[2];
  const float* ab  = (const float*)d_in[3];
  const float* cw  = (const float*)d_in[4];
  const float* cb  = (const float*)d_in[5];
  const float* mag = (const float*)d_in[6];
  const int* bidx    = (const int*)d_in[7];
  const int* in_idx  = (const int*)d_in[8];
  const int* out_idx = (const int*)d_in[9];
  float* out = (float*)d_out;
  char* ws = (char*)d_ws;

  float* styles = (float*)(ws + 0);         // 2048 B
  float* sn     = (float*)(ws + 2048);      // 2048 B
  float* wnorm  = (float*)(ws + 4096);      // 512 B
  float* dco2   = (float*)(ws + 4608);      // 2048 B
  float* vmat   = (float*)(ws + 8192);      // 65536 B
  unsigned short* bpack = (unsigned short*)(ws + 73728);    // 884736 B
  unsigned short* xpad  = (unsigned short*)(ws + 958464);   // 33554688 B
  int* invT     = (int*)(ws + 34513152);                    // 14155776 B -> end 48668928

  k_prep_w<<<128, 128, 0, stream>>>(cw, wnorm, vmat, bpack);
  k_styles_dot<<<128, 256, 0, stream>>>(w, aw, ab, styles);
  k_snorm<<<1, 512, 0, stream>>>(styles, sn);
  k_dcoefs2<<<64, 512, 0, stream>>>(vmat, sn, wnorm, mag, dco2);
  k_xmod<<<16385, 256, 0, stream>>>(x, sn, bidx, xpad);
  dim3 gi(512, 27);
  k_invinit<<<gi, 256, 0, stream>>>(invT);
  k_invscat<<<gi, 256, 0, stream>>>(out_idx, in_idx, invT);
  k_conv<<<1024, 512, 0, stream>>>(xpad, bpack, invT, dco2, cb, bidx, out);
}